// Round 6
// baseline (68.872 us; speedup 1.0000x reference)
//
#include <hip/hip_runtime.h>

// input x: (B=256,T=600,J=25,C=3) f32; x[b,tt,n*5+p,c] = in[(b*600+tt)*75 + n*15 + p*3 + c]
// output: (B,5,1800,4,4) f32, windows concatenated along tout.
// For global time tt the 3 window groups' outputs sit at tout = tt, 600+tt, 1200+tt.
// Interior slots: 3-time covariance around mu(tt); window-boundary slots: center-only.
//
// R6: block = (b, 100-tt chunk). Phase 0 stages the chunk's raw rows (with +-1 halo,
// 102x75 floats = 30.6 KB) into LDS via dense stride-1 dword loads (coalesced, ~30
// instrs/thread vs R5's 35 lane-scattered ones). Phase 1: thread-per-slot computes
// moments directly from LDS (bank stride 75%32=11 -> conflict-free) and stores in
// near-sequential streams (runs of 100 slots, <=2 streams/wave).

#define T_ 600
#define CH_ 100
#define NCH_ 6   // 600/100

__global__ __launch_bounds__(256) void gauss_agg_kernel(const float* __restrict__ x,
                                                        float* __restrict__ out) {
    __shared__ float raw[102 * 75];   // 30.6 KB

    int blk = blockIdx.x;
    int chunk = blk % NCH_;
    int b = blk / NCH_;

    int start = chunk * CH_ - 1; if (start < 0) start = 0;
    int end = chunk * CH_ + CH_ + 1; if (end > T_) end = T_;
    int total = (end - start) * 75;

    // ---- phase 0: dense coalesced stage ----
    const float* src = x + ((size_t)b * T_ + start) * 75;
    for (int e = (int)threadIdx.x; e < total; e += 256) raw[e] = src[e];
    __syncthreads();

    int ofs = (chunk == 0) ? 0 : 1;   // local row for tt is (tt - chunk*CH_) + ofs
    const float w5[5] = {4.f, 2.f, 3.f, 2.f, 4.f};

    // ---- phase 1: 1500 slots = 5n x 3w x 100tl ----
    for (int r = 0; r < 6; ++r) {
        int s = r * 256 + (int)threadIdx.x;
        if (s >= 1500) break;
        int n  = s / 300;
        int q  = s - n * 300;
        int w  = q / 100;
        int tl = q - w * 100;
        int tt = chunk * CH_ + tl;
        int li = tl + ofs;

        bool boundary;
        if (w == 0)      boundary = (tt == 0) || (tt == 599);
        else if (w == 1) boundary = (tt == 0) || (tt == 299) || (tt == 300) || (tt == 599);
        else             boundary = (tt == 0) || (tt == 199) || (tt == 200) ||
                                    (tt == 399) || (tt == 400) || (tt == 599);

        const float* rc = &raw[li * 75 + n * 15];

        float s0=0.f,s1=0.f,s2=0.f, m0=0.f,m1=0.f,m2=0.f;
        float A00=0.f,A01=0.f,A02=0.f,A11=0.f,A12=0.f,A22=0.f;
        #pragma unroll
        for (int p = 0; p < 5; ++p) {
            float a = rc[p*3+0], c = rc[p*3+1], d = rc[p*3+2];
            s0 += a; s1 += c; s2 += d;
            m0 += w5[p]*a; m1 += w5[p]*c; m2 += w5[p]*d;
            A00 += a*a; A01 += a*c; A02 += a*d;
            A11 += c*c; A12 += c*d; A22 += d*d;
        }
        float mu0 = m0*(1.f/15.f), mu1 = m1*(1.f/15.f), mu2 = m2*(1.f/15.f);

        float inv = 0.2f;
        if (!boundary) {   // interior: tt-1 and tt+1 both staged
            #pragma unroll
            for (int dstep = 0; dstep < 2; ++dstep) {
                const float* rn = rc + (dstep ? 75 : -75);
                #pragma unroll
                for (int p = 0; p < 5; ++p) {
                    float a = rn[p*3+0], c = rn[p*3+1], d = rn[p*3+2];
                    s0 += a; s1 += c; s2 += d;
                    A00 += a*a; A01 += a*c; A02 += a*d;
                    A11 += c*c; A12 += c*d; A22 += d*d;
                }
            }
            inv = 1.f/15.f;
        }

        float mb0 = s0*inv, mb1 = s1*inv, mb2 = s2*inv;
        float e00 = A00*inv - 2.f*mu0*mb0 + 2.f*mu0*mu0;
        float e01 = A01*inv - mu0*mb1 - mb0*mu1 + 2.f*mu0*mu1;
        float e02 = A02*inv - mu0*mb2 - mb0*mu2 + 2.f*mu0*mu2;
        float e11 = A11*inv - 2.f*mu1*mb1 + 2.f*mu1*mu1;
        float e12 = A12*inv - mu1*mb2 - mb1*mu2 + 2.f*mu1*mu2;
        float e22 = A22*inv - 2.f*mu2*mb2 + 2.f*mu2*mu2;

        float4* op = reinterpret_cast<float4*>(out)
                   + ((size_t)(b * 5 + n) * 1800 + w * 600 + tt) * 4;
        op[0] = make_float4(e00, e01, e02, mu0);
        op[1] = make_float4(e01, e11, e12, mu1);
        op[2] = make_float4(e02, e12, e22, mu2);
        op[3] = make_float4(mu0, mu1, mu2, 1.f);
    }
}

extern "C" void kernel_launch(void* const* d_in, const int* in_sizes, int n_in,
                              void* d_out, int out_size, void* d_ws, size_t ws_size,
                              hipStream_t stream) {
    const float* x = (const float*)d_in[0];
    float* out = (float*)d_out;
    gauss_agg_kernel<<<256 * NCH_, 256, 0, stream>>>(x, out);
}

// Round 7
// 42.131 us; speedup vs baseline: 1.6347x; 1.6347x over previous
//
#include <hip/hip_runtime.h>

// input x: (B=256,T=600,J=25,C=3) f32; x[b,tt,n*5+p,c] = in[(b*600+tt)*75 + n*15 + p*3 + c]
// output: (B,5,1800,4,4) f32, windows concatenated along tout.
//
// R7: R6's staged compute + LDS-transposed STORE phase. Each 256-slot batch is
// written to a bank-padded LDS buffer (80B/slot), then stored cooperatively with
// lane-contiguous addressing: store instr k, lane t -> output float4 (k*256+t),
// giving 2-3 contiguous 128B segments per instruction instead of 32.

#define T_ 600
#define CH_ 100
#define NCH_ 6

__global__ __launch_bounds__(256) void gauss_agg_kernel(const float* __restrict__ x,
                                                        float* __restrict__ out) {
    __shared__ float raw[102 * 75];      // 30.6 KB staged input (chunk + halo)
    __shared__ float4 obuf[256 * 5];     // 20 KB; slot stride 5 float4 (80B) kills bank aliasing

    int blk = blockIdx.x;
    int ch  = blk % NCH_;
    int b   = blk / NCH_;

    int start = ch * CH_ - 1; if (start < 0) start = 0;
    int end   = ch * CH_ + CH_ + 1; if (end > T_) end = T_;
    int total = (end - start) * 75;

    // ---- phase 0: dense coalesced stage ----
    const float* src = x + ((size_t)b * T_ + start) * 75;
    for (int e = (int)threadIdx.x; e < total; e += 256) raw[e] = src[e];
    __syncthreads();

    int ofs = (ch == 0) ? 0 : 1;     // local row of tt = (tt - ch*CH_) + ofs
    const float w5[5] = {4.f, 2.f, 3.f, 2.f, 4.f};
    float4* outf4 = reinterpret_cast<float4*>(out);

    // ---- 6 batches of 256 slots (1500 = 5n x 3w x 100tt) ----
    for (int m = 0; m < 6; ++m) {
        int s = m * 256 + (int)threadIdx.x;
        if (s < 1500) {
            int n  = s / 300;
            int q  = s - n * 300;
            int w  = q / 100;
            int tl = q - w * 100;
            int tt = ch * CH_ + tl;
            int li = tl + ofs;

            bool boundary;
            if (w == 0)      boundary = (tt == 0) || (tt == 599);
            else if (w == 1) boundary = (tt == 0) || (tt == 299) || (tt == 300) || (tt == 599);
            else             boundary = (tt == 0) || (tt == 199) || (tt == 200) ||
                                        (tt == 399) || (tt == 400) || (tt == 599);

            const float* rc = &raw[li * 75 + n * 15];

            float s0=0.f,s1=0.f,s2=0.f, m0=0.f,m1=0.f,m2=0.f;
            float A00=0.f,A01=0.f,A02=0.f,A11=0.f,A12=0.f,A22=0.f;
            #pragma unroll
            for (int p = 0; p < 5; ++p) {
                float a = rc[p*3+0], c = rc[p*3+1], d = rc[p*3+2];
                s0 += a; s1 += c; s2 += d;
                m0 += w5[p]*a; m1 += w5[p]*c; m2 += w5[p]*d;
                A00 += a*a; A01 += a*c; A02 += a*d;
                A11 += c*c; A12 += c*d; A22 += d*d;
            }
            float mu0 = m0*(1.f/15.f), mu1 = m1*(1.f/15.f), mu2 = m2*(1.f/15.f);

            float inv = 0.2f;
            if (!boundary) {
                #pragma unroll
                for (int dstep = 0; dstep < 2; ++dstep) {
                    const float* rn = rc + (dstep ? 75 : -75);
                    #pragma unroll
                    for (int p = 0; p < 5; ++p) {
                        float a = rn[p*3+0], c = rn[p*3+1], d = rn[p*3+2];
                        s0 += a; s1 += c; s2 += d;
                        A00 += a*a; A01 += a*c; A02 += a*d;
                        A11 += c*c; A12 += c*d; A22 += d*d;
                    }
                }
                inv = 1.f/15.f;
            }

            float mb0 = s0*inv, mb1 = s1*inv, mb2 = s2*inv;
            float e00 = A00*inv - 2.f*mu0*mb0 + 2.f*mu0*mu0;
            float e01 = A01*inv - mu0*mb1 - mb0*mu1 + 2.f*mu0*mu1;
            float e02 = A02*inv - mu0*mb2 - mb0*mu2 + 2.f*mu0*mu2;
            float e11 = A11*inv - 2.f*mu1*mb1 + 2.f*mu1*mu1;
            float e12 = A12*inv - mu1*mb2 - mb1*mu2 + 2.f*mu1*mu2;
            float e22 = A22*inv - 2.f*mu2*mb2 + 2.f*mu2*mu2;

            int base = (int)threadIdx.x * 5;
            obuf[base + 0] = make_float4(e00, e01, e02, mu0);
            obuf[base + 1] = make_float4(e01, e11, e12, mu1);
            obuf[base + 2] = make_float4(e02, e12, e22, mu2);
            obuf[base + 3] = make_float4(mu0, mu1, mu2, 1.f);
        }
        __syncthreads();

        // ---- cooperative lane-contiguous store of this batch ----
        int nslots  = (1500 - m * 256 < 256) ? (1500 - m * 256) : 256;
        int npieces = nslots * 4;
        #pragma unroll
        for (int k = 0; k < 4; ++k) {
            int f = k * 256 + (int)threadIdx.x;
            if (f < npieces) {
                int sl = f >> 2, pc = f & 3;
                int s2 = m * 256 + sl;
                int n  = s2 / 300;
                int q  = s2 - n * 300;
                int w  = q / 100;
                int tl = q - w * 100;
                int tt = ch * CH_ + tl;
                size_t o = ((size_t)(b * 5 + n) * 1800 + w * 600 + tt) * 4 + pc;
                outf4[o] = obuf[sl * 5 + pc];
            }
        }
        __syncthreads();
    }
}

extern "C" void kernel_launch(void* const* d_in, const int* in_sizes, int n_in,
                              void* d_out, int out_size, void* d_ws, size_t ws_size,
                              hipStream_t stream) {
    const float* x = (const float*)d_in[0];
    float* out = (float*)d_out;
    gauss_agg_kernel<<<256 * NCH_, 256, 0, stream>>>(x, out);
}